// Round 1
// baseline (1014.375 us; speedup 1.0000x reference)
//
#include <hip/hip_runtime.h>
#include <stdint.h>

// S3FD anchor assignment.
// d_in[0]: anchor [N,4] f32, d_in[1]: gt [M,4] f32. d_out: assign [N] int32.
//
// Key encoding for exact jax.lax.top_k semantics (stable, lower index first on
// ties): key = (float_bits(iou) << 32) | ~anchor_idx.  iou >= 0 so float bits
// are monotone as unsigned; larger key = better (higher iou, then lower idx).

#define POS_THRESH 0.5f
#define NEG_THRESH 0.3f
#define CLAIM_THRESH 0.1f

constexpr int GPB = 8;       // GTs per block in the top-k partial kernel
constexpr int MAXM = 256;    // capacity for per-GT LDS tables (M = 200)

__device__ __forceinline__ void ins3(unsigned long long& t0,
                                     unsigned long long& t1,
                                     unsigned long long& t2,
                                     unsigned long long k) {
    if (k > t2) {
        if (k > t0)      { t2 = t1; t1 = t0; t0 = k; }
        else if (k > t1) { t2 = t1; t1 = k; }
        else             { t2 = k; }
    }
}

__device__ __forceinline__ unsigned long long shfl_xor_u64(unsigned long long x,
                                                           int mask) {
    int lo = __shfl_xor((int)(unsigned)x, mask, 64);
    int hi = __shfl_xor((int)(unsigned)(x >> 32), mask, 64);
    return ((unsigned long long)(unsigned)hi << 32) | (unsigned)lo;
}

// ---------------------------------------------------------------------------
// Kernel 1: per-anchor max/argmax IoU over all GTs -> base assignment
// ---------------------------------------------------------------------------
__global__ void __launch_bounds__(256) k_base_assign(
    const float4* __restrict__ anchor, const float4* __restrict__ gt,
    int* __restrict__ out, int N, int M)
{
    __shared__ float4 sbox[MAXM];
    __shared__ float  sarea[MAXM];
    int tid = threadIdx.x;
    for (int m = tid; m < M; m += blockDim.x) {
        float4 g = gt[m];
        sbox[m]  = g;
        sarea[m] = (g.z - g.x) * (g.w - g.y);
    }
    __syncthreads();

    int i = blockIdx.x * blockDim.x + tid;
    if (i >= N) return;

    float4 a = anchor[i];
    float area_a = (a.z - a.x) * (a.w - a.y);

    float best = -1.0f;
    int   bidx = 0;
    for (int m = 0; m < M; ++m) {
        float4 g = sbox[m];
        float ltx = fmaxf(a.x, g.x), lty = fmaxf(a.y, g.y);
        float rbx = fminf(a.z, g.z), rby = fminf(a.w, g.w);
        float w = fmaxf(rbx - ltx, 0.0f), h = fmaxf(rby - lty, 0.0f);
        float inter = w * h;
        float iou = 0.0f;
        if (inter > 0.0f) iou = inter / ((area_a + sarea[m]) - inter);
        if (iou > best) { best = iou; bidx = m; }   // strict > : first max wins
    }
    // assign = -2; < NEG -> -1; > POS -> argmax   (exclusive ranges)
    int v = -2;
    if (best < NEG_THRESH) v = -1;
    if (best > POS_THRESH) v = bidx;
    out[i] = v;
}

// ---------------------------------------------------------------------------
// Kernel 2: per-(GT, anchor-chunk) top-3 partials -> d_ws
// grid: (nchunk, ceil(M/GPB)), block 256
// ---------------------------------------------------------------------------
__global__ void __launch_bounds__(256) k_topk_partial(
    const float4* __restrict__ anchor, const float4* __restrict__ gt,
    unsigned long long* __restrict__ partial, int N, int M, int chunk, int nchunk)
{
    int tid = threadIdx.x;
    int g0  = blockIdx.y * GPB;

    float4 gb[GPB];
    float  ga[GPB];
#pragma unroll
    for (int j = 0; j < GPB; ++j) {
        int m = g0 + j;
        float4 g = (m < M) ? gt[m] : make_float4(0.f, 0.f, 0.f, 0.f);
        gb[j] = g;
        ga[j] = (g.z - g.x) * (g.w - g.y);
    }

    unsigned long long t[GPB][3];
#pragma unroll
    for (int j = 0; j < GPB; ++j) { t[j][0] = 0; t[j][1] = 0; t[j][2] = 0; }

    int start = blockIdx.x * chunk;
    int end   = min(start + chunk, N);
    for (int i = start + tid; i < end; i += 256) {
        float4 a = anchor[i];
        float area_a = (a.z - a.x) * (a.w - a.y);
        unsigned idxkey = ~(unsigned)i;
#pragma unroll
        for (int j = 0; j < GPB; ++j) {
            float ltx = fmaxf(a.x, gb[j].x), lty = fmaxf(a.y, gb[j].y);
            float rbx = fminf(a.z, gb[j].z), rby = fminf(a.w, gb[j].w);
            float w = fmaxf(rbx - ltx, 0.0f), h = fmaxf(rby - lty, 0.0f);
            float inter = w * h;
            float iou = 0.0f;
            if (inter > 0.0f) iou = inter / ((area_a + ga[j]) - inter);
            unsigned long long key =
                ((unsigned long long)__float_as_uint(iou) << 32) | idxkey;
            ins3(t[j][0], t[j][1], t[j][2], key);
        }
    }

    // wave butterfly: every lane ends with the wave's top-3 per GT
    for (int off = 1; off < 64; off <<= 1) {
#pragma unroll
        for (int j = 0; j < GPB; ++j) {
            unsigned long long o0 = shfl_xor_u64(t[j][0], off);
            unsigned long long o1 = shfl_xor_u64(t[j][1], off);
            unsigned long long o2 = shfl_xor_u64(t[j][2], off);
            ins3(t[j][0], t[j][1], t[j][2], o0);
            ins3(t[j][0], t[j][1], t[j][2], o1);
            ins3(t[j][0], t[j][1], t[j][2], o2);
        }
    }

    __shared__ unsigned long long red[4][GPB][3];
    int wave = tid >> 6;
    int lane = tid & 63;
    if (lane == 0) {
#pragma unroll
        for (int j = 0; j < GPB; ++j) {
            red[wave][j][0] = t[j][0];
            red[wave][j][1] = t[j][1];
            red[wave][j][2] = t[j][2];
        }
    }
    __syncthreads();

    if (tid < GPB) {
        int m = g0 + tid;
        if (m < M) {
            unsigned long long r0 = 0, r1 = 0, r2 = 0;
            for (int wv = 0; wv < 4; ++wv) {
                ins3(r0, r1, r2, red[wv][tid][0]);
                ins3(r0, r1, r2, red[wv][tid][1]);
                ins3(r0, r1, r2, red[wv][tid][2]);
            }
            size_t base = ((size_t)m * nchunk + blockIdx.x) * 3;
            partial[base + 0] = r0;
            partial[base + 1] = r1;
            partial[base + 2] = r2;
        }
    }
}

// ---------------------------------------------------------------------------
// Kernel 3: merge partials -> global top-3 per GT; apply forced claims.
// Single block. "Later gt overwrites earlier" == scatter-max over gt index.
// ---------------------------------------------------------------------------
__global__ void __launch_bounds__(256) k_finalize(
    const unsigned long long* __restrict__ partial, int* __restrict__ out,
    int M, int nchunk)
{
    __shared__ int s_a[3 * MAXM];
    __shared__ int s_cv[3 * MAXM];
    int tid = threadIdx.x;

    if (tid < M) {
        unsigned long long r0 = 0, r1 = 0, r2 = 0;
        const unsigned long long* p = partial + (size_t)tid * nchunk * 3;
        int tot = nchunk * 3;
        for (int c = 0; c < tot; ++c) ins3(r0, r1, r2, p[c]);

        float v0 = __uint_as_float((unsigned)(r0 >> 32));
        float v1 = __uint_as_float((unsigned)(r1 >> 32));
        float v2 = __uint_as_float((unsigned)(r2 >> 32));
        int a0 = (int)(~(unsigned)(r0 & 0xffffffffULL));
        int a1 = (int)(~(unsigned)(r1 & 0xffffffffULL));
        int a2 = (int)(~(unsigned)(r2 & 0xffffffffULL));

        int npos = (v0 > POS_THRESH) + (v1 > POS_THRESH) + (v2 > POS_THRESH);
        bool low = npos < 3;

        s_a[tid * 3 + 0] = a0;
        s_a[tid * 3 + 1] = a1;
        s_a[tid * 3 + 2] = a2;
        s_cv[tid * 3 + 0] = tid;                                    // k==0 always
        s_cv[tid * 3 + 1] = (low && v1 > CLAIM_THRESH) ? tid : -1;
        s_cv[tid * 3 + 2] = (low && v2 > CLAIM_THRESH) ? tid : -1;
    }
    __syncthreads();

    int tot = 3 * M;
    for (int e = tid; e < tot; e += blockDim.x) {
        int cv = s_cv[e];
        if (cv < 0) continue;
        int a = s_a[e];
        bool win = true;
        for (int f = 0; f < tot; ++f) {
            if (s_cv[f] > cv && s_a[f] == a) { win = false; break; }
        }
        if (win) out[a] = cv;   // forced >= 0 overrides base assignment
    }
}

// ---------------------------------------------------------------------------
extern "C" void kernel_launch(void* const* d_in, const int* in_sizes, int n_in,
                              void* d_out, int out_size, void* d_ws, size_t ws_size,
                              hipStream_t stream) {
    const float4* anchor = (const float4*)d_in[0];
    const float4* gt     = (const float4*)d_in[1];
    int N = in_sizes[0] / 4;
    int M = in_sizes[1] / 4;
    int* out = (int*)d_out;

    int nchunk = 64;
    size_t need = (size_t)M * nchunk * 3 * sizeof(unsigned long long);
    if (need > ws_size) {
        nchunk = (int)(ws_size / ((size_t)M * 3 * sizeof(unsigned long long)));
        if (nchunk < 1) nchunk = 1;
    }
    unsigned long long* partial = (unsigned long long*)d_ws;

    dim3 g1((N + 255) / 256);
    k_base_assign<<<g1, 256, 0, stream>>>(anchor, gt, out, N, M);

    int ngroup = (M + GPB - 1) / GPB;
    int chunk  = (N + nchunk - 1) / nchunk;
    dim3 g2(nchunk, ngroup);
    k_topk_partial<<<g2, 256, 0, stream>>>(anchor, gt, partial, N, M, chunk, nchunk);

    k_finalize<<<1, 256, 0, stream>>>(partial, out, M, nchunk);
}

// Round 2
// 954.920 us; speedup vs baseline: 1.0623x; 1.0623x over previous
//
#include <hip/hip_runtime.h>
#include <stdint.h>

// S3FD anchor assignment.
// d_in[0]: anchor [N,4] f32, d_in[1]: gt [M,4] f32. d_out: assign [N] int32.
//
// Key encoding for exact jax.lax.top_k semantics (stable, lower index first on
// ties): key = (float_bits(iou) << 32) | ~anchor_idx.  iou >= 0 so float bits
// are monotone as unsigned; larger key = better (higher iou, then lower idx).
//
// NOTE: all per-thread top-3 state is kept in NAMED SCALARS (macro-generated)
// — array accumulators were variable-indexed pre-unroll, defeated SROA, and
// went to scratch (round 0: VGPR=28, 2.2 GB scratch traffic, 720 us).

#define POS_THRESH 0.5f
#define NEG_THRESH 0.3f
#define CLAIM_THRESH 0.1f

constexpr int GPB = 4;       // GTs per block in the top-k partial kernel
constexpr int MAXM = 256;    // capacity for per-GT LDS tables (M = 200)

__device__ __forceinline__ void ins3(unsigned long long& t0,
                                     unsigned long long& t1,
                                     unsigned long long& t2,
                                     unsigned long long k) {
    if (k > t2) {
        if (k > t0)      { t2 = t1; t1 = t0; t0 = k; }
        else if (k > t1) { t2 = t1; t1 = k; }
        else             { t2 = k; }
    }
}

__device__ __forceinline__ unsigned long long shfl_xor_u64(unsigned long long x,
                                                           int mask) {
    int lo = __shfl_xor((int)(unsigned)x, mask, 64);
    int hi = __shfl_xor((int)(unsigned)(x >> 32), mask, 64);
    return ((unsigned long long)(unsigned)hi << 32) | (unsigned)lo;
}

// ---------------------------------------------------------------------------
// Kernel 1: per-anchor max/argmax IoU over all GTs -> base assignment.
// 2 anchors per thread to amortize the LDS broadcast reads.
// ---------------------------------------------------------------------------
__global__ void __launch_bounds__(256) k_base_assign(
    const float4* __restrict__ anchor, const float4* __restrict__ gt,
    int* __restrict__ out, int N, int M)
{
    __shared__ float4 sbox[MAXM];
    __shared__ float  sarea[MAXM];
    int tid = threadIdx.x;
    for (int m = tid; m < M; m += blockDim.x) {
        float4 g = gt[m];
        sbox[m]  = g;
        sarea[m] = (g.z - g.x) * (g.w - g.y);
    }
    __syncthreads();

    int i0 = (blockIdx.x * blockDim.x + tid) * 2;
    if (i0 >= N) return;
    bool two = (i0 + 1) < N;

    float4 a0 = anchor[i0];
    float4 a1 = two ? anchor[i0 + 1] : a0;
    float area0 = (a0.z - a0.x) * (a0.w - a0.y);
    float area1 = (a1.z - a1.x) * (a1.w - a1.y);

    float best0 = -1.0f, best1 = -1.0f;
    int   bidx0 = 0,     bidx1 = 0;
    for (int m = 0; m < M; ++m) {
        float4 g = sbox[m];
        float ag = sarea[m];
        {
            float ltx = fmaxf(a0.x, g.x), lty = fmaxf(a0.y, g.y);
            float rbx = fminf(a0.z, g.z), rby = fminf(a0.w, g.w);
            float w = fmaxf(rbx - ltx, 0.0f), h = fmaxf(rby - lty, 0.0f);
            float inter = w * h;
            float iou = 0.0f;
            if (inter > 0.0f) iou = inter / ((area0 + ag) - inter);
            if (iou > best0) { best0 = iou; bidx0 = m; }  // strict >: first max
        }
        {
            float ltx = fmaxf(a1.x, g.x), lty = fmaxf(a1.y, g.y);
            float rbx = fminf(a1.z, g.z), rby = fminf(a1.w, g.w);
            float w = fmaxf(rbx - ltx, 0.0f), h = fmaxf(rby - lty, 0.0f);
            float inter = w * h;
            float iou = 0.0f;
            if (inter > 0.0f) iou = inter / ((area1 + ag) - inter);
            if (iou > best1) { best1 = iou; bidx1 = m; }
        }
    }
    int v0 = -2;
    if (best0 < NEG_THRESH) v0 = -1;
    if (best0 > POS_THRESH) v0 = bidx0;
    out[i0] = v0;
    if (two) {
        int v1 = -2;
        if (best1 < NEG_THRESH) v1 = -1;
        if (best1 > POS_THRESH) v1 = bidx1;
        out[i0 + 1] = v1;
    }
}

// ---------------------------------------------------------------------------
// Kernel 2: per-(GT, anchor-chunk) top-3 partials -> d_ws
// grid: (nchunk, ceil(M/GPB)), block 256.  All accumulators are named scalars.
// ---------------------------------------------------------------------------
__global__ void __launch_bounds__(256) k_topk_partial(
    const float4* __restrict__ anchor, const float4* __restrict__ gt,
    unsigned long long* __restrict__ partial, int N, int M, int chunk, int nchunk)
{
    int tid = threadIdx.x;
    int g0  = blockIdx.y * GPB;

#define DECL_GT(j) \
    float gx1_##j, gy1_##j, gx2_##j, gy2_##j, ga_##j; \
    unsigned long long t0_##j = 0, t1_##j = 0, t2_##j = 0;
    DECL_GT(0) DECL_GT(1) DECL_GT(2) DECL_GT(3)

#define LOAD_GT(j) { int m = g0 + j; \
    float4 g = (m < M) ? gt[m] : make_float4(0.f, 0.f, 0.f, 0.f); \
    gx1_##j = g.x; gy1_##j = g.y; gx2_##j = g.z; gy2_##j = g.w; \
    ga_##j = (g.z - g.x) * (g.w - g.y); }
    LOAD_GT(0) LOAD_GT(1) LOAD_GT(2) LOAD_GT(3)

    int start = blockIdx.x * chunk;
    int end   = min(start + chunk, N);
    for (int i = start + tid; i < end; i += 256) {
        float4 a = anchor[i];
        float area_a = (a.z - a.x) * (a.w - a.y);
        unsigned idxkey = ~(unsigned)i;
#define PAIR(j) { \
        float ltx = fmaxf(a.x, gx1_##j), lty = fmaxf(a.y, gy1_##j); \
        float rbx = fminf(a.z, gx2_##j), rby = fminf(a.w, gy2_##j); \
        float w = fmaxf(rbx - ltx, 0.0f), h = fmaxf(rby - lty, 0.0f); \
        float inter = w * h; \
        float iou = 0.0f; \
        if (inter > 0.0f) iou = inter / ((area_a + ga_##j) - inter); \
        unsigned long long key = \
            ((unsigned long long)__float_as_uint(iou) << 32) | idxkey; \
        ins3(t0_##j, t1_##j, t2_##j, key); }
        PAIR(0) PAIR(1) PAIR(2) PAIR(3)
    }

    // wave butterfly: every lane ends with the wave's top-3 per GT
    for (int off = 1; off < 64; off <<= 1) {
#define BFLY(j) { \
        unsigned long long o0 = shfl_xor_u64(t0_##j, off); \
        unsigned long long o1 = shfl_xor_u64(t1_##j, off); \
        unsigned long long o2 = shfl_xor_u64(t2_##j, off); \
        ins3(t0_##j, t1_##j, t2_##j, o0); \
        ins3(t0_##j, t1_##j, t2_##j, o1); \
        ins3(t0_##j, t1_##j, t2_##j, o2); }
        BFLY(0) BFLY(1) BFLY(2) BFLY(3)
    }

    __shared__ unsigned long long red[4][GPB][3];
    int wave = tid >> 6;
    int lane = tid & 63;
    if (lane == 0) {
#define STORE_W(j) { red[wave][j][0] = t0_##j; red[wave][j][1] = t1_##j; \
                     red[wave][j][2] = t2_##j; }
        STORE_W(0) STORE_W(1) STORE_W(2) STORE_W(3)
    }
    __syncthreads();

    if (tid < GPB) {
        int m = g0 + tid;
        if (m < M) {
            unsigned long long r0 = 0, r1 = 0, r2 = 0;
            for (int wv = 0; wv < 4; ++wv) {
                ins3(r0, r1, r2, red[wv][tid][0]);
                ins3(r0, r1, r2, red[wv][tid][1]);
                ins3(r0, r1, r2, red[wv][tid][2]);
            }
            size_t base = ((size_t)m * nchunk + blockIdx.x) * 3;
            partial[base + 0] = r0;
            partial[base + 1] = r1;
            partial[base + 2] = r2;
        }
    }
}

// ---------------------------------------------------------------------------
// Kernel 3: merge partials -> global top-3 per GT; apply forced claims.
// Single block. "Later gt overwrites earlier" == scatter-max over gt index.
// ---------------------------------------------------------------------------
__global__ void __launch_bounds__(256) k_finalize(
    const unsigned long long* __restrict__ partial, int* __restrict__ out,
    int M, int nchunk)
{
    __shared__ int s_a[3 * MAXM];
    __shared__ int s_cv[3 * MAXM];
    int tid = threadIdx.x;

    if (tid < M) {
        unsigned long long r0 = 0, r1 = 0, r2 = 0;
        const unsigned long long* p = partial + (size_t)tid * nchunk * 3;
        int tot = nchunk * 3;
        for (int c = 0; c < tot; ++c) ins3(r0, r1, r2, p[c]);

        float v0 = __uint_as_float((unsigned)(r0 >> 32));
        float v1 = __uint_as_float((unsigned)(r1 >> 32));
        float v2 = __uint_as_float((unsigned)(r2 >> 32));
        int a0 = (int)(~(unsigned)(r0 & 0xffffffffULL));
        int a1 = (int)(~(unsigned)(r1 & 0xffffffffULL));
        int a2 = (int)(~(unsigned)(r2 & 0xffffffffULL));

        int npos = (v0 > POS_THRESH) + (v1 > POS_THRESH) + (v2 > POS_THRESH);
        bool low = npos < 3;

        s_a[tid * 3 + 0] = a0;
        s_a[tid * 3 + 1] = a1;
        s_a[tid * 3 + 2] = a2;
        s_cv[tid * 3 + 0] = tid;                                    // k==0 always
        s_cv[tid * 3 + 1] = (low && v1 > CLAIM_THRESH) ? tid : -1;
        s_cv[tid * 3 + 2] = (low && v2 > CLAIM_THRESH) ? tid : -1;
    }
    __syncthreads();

    int tot = 3 * M;
    for (int e = tid; e < tot; e += blockDim.x) {
        int cv = s_cv[e];
        if (cv < 0) continue;
        int a = s_a[e];
        bool win = true;
        for (int f = 0; f < tot; ++f) {
            if (s_cv[f] > cv && s_a[f] == a) { win = false; break; }
        }
        if (win) out[a] = cv;   // forced >= 0 overrides base assignment
    }
}

// ---------------------------------------------------------------------------
extern "C" void kernel_launch(void* const* d_in, const int* in_sizes, int n_in,
                              void* d_out, int out_size, void* d_ws, size_t ws_size,
                              hipStream_t stream) {
    const float4* anchor = (const float4*)d_in[0];
    const float4* gt     = (const float4*)d_in[1];
    int N = in_sizes[0] / 4;
    int M = in_sizes[1] / 4;
    int* out = (int*)d_out;

    int nchunk = 64;
    size_t need = (size_t)M * nchunk * 3 * sizeof(unsigned long long);
    if (need > ws_size) {
        nchunk = (int)(ws_size / ((size_t)M * 3 * sizeof(unsigned long long)));
        if (nchunk < 1) nchunk = 1;
    }
    unsigned long long* partial = (unsigned long long*)d_ws;

    dim3 g1(((N + 1) / 2 + 255) / 256);
    k_base_assign<<<g1, 256, 0, stream>>>(anchor, gt, out, N, M);

    int ngroup = (M + GPB - 1) / GPB;
    int chunk  = (N + nchunk - 1) / nchunk;
    dim3 g2(nchunk, ngroup);
    k_topk_partial<<<g2, 256, 0, stream>>>(anchor, gt, partial, N, M, chunk, nchunk);

    k_finalize<<<1, 256, 0, stream>>>(partial, out, M, nchunk);
}

// Round 3
// 503.435 us; speedup vs baseline: 2.0149x; 1.8968x over previous
//
#include <hip/hip_runtime.h>
#include <stdint.h>

// S3FD anchor assignment — fused single-pass design.
// d_in[0]: anchor [N,4] f32, d_in[1]: gt [M,4] f32. d_out: assign [N] int32.
//
// Round 0-2 post-mortem: the chunked per-thread top-3 kernel moved ~2 GB of
// HBM traffic per dispatch (alg footprint: 8 MB) — per-pair scratch
// round-trips plus 50x anchor re-reads. This version transposes the work:
// each LANE owns 4 GT slots entirely in registers (box, area, top-3 keys as
// named scalars); anchors stream through LDS once; the per-anchor argmax
// (base assignment) is computed from the same IoU evaluations via a u64
// butterfly. No per-thread state larger than ~30 named scalars, no arrays.
//
// Key encodings (exact jax semantics):
//   per-GT top-3:  key = (iou_bits << 32) | ~anchor_idx   (stable top_k:
//                  higher iou, then lower anchor index wins)
//   per-anchor:    key = (iou_bits << 32) | ~gt_idx       (argmax first-max:
//                  higher iou, then lower gt index wins)

#define POS_THRESH 0.5f
#define NEG_THRESH 0.3f
#define CLAIM_THRESH 0.1f

constexpr int MPAD = 256;    // padded GT count (M = 200)

#define INS3(t0, t1, t2, k) do {                                  \
    if ((k) > (t2)) {                                             \
        if ((k) > (t0))      { t2 = t1; t1 = t0; t0 = (k); }      \
        else if ((k) > (t1)) { t2 = t1; t1 = (k); }               \
        else                 { t2 = (k); }                        \
    } } while (0)

// ---------------------------------------------------------------------------
// Fused kernel: base assignment + per-(block,GT) top-3 partials.
// grid = ceil(N/slice) blocks x 256 threads; slice is a multiple of 256.
// ---------------------------------------------------------------------------
__global__ void __launch_bounds__(256) k_fused(
    const float4* __restrict__ anchor, const float4* __restrict__ gt,
    int* __restrict__ out, unsigned long long* __restrict__ partial,
    int N, int M, int slice)
{
    __shared__ float4 s_abox[256];
    __shared__ float  s_aarea[256];
    __shared__ unsigned long long s_merge[4][64][4][3];   // 24 KB

    const int tid  = threadIdx.x;
    const int lane = tid & 63;
    const int w    = tid >> 6;

    // ---- per-lane GT state: 4 GTs, all named scalars --------------------
#define GTDECL(r)                                                  \
    float gx1_##r, gy1_##r, gx2_##r, gy2_##r, ga_##r;             \
    unsigned nm_##r;                                               \
    unsigned long long t0_##r = 0, t1_##r = 0, t2_##r = 0;
    GTDECL(0) GTDECL(1) GTDECL(2) GTDECL(3)

#define GTLOAD(r) {                                                \
    int m = lane + (r) * 64;                                       \
    float4 g = (m < M) ? gt[m] : make_float4(0.f, 0.f, 0.f, 0.f);  \
    gx1_##r = g.x; gy1_##r = g.y; gx2_##r = g.z; gy2_##r = g.w;    \
    ga_##r = (g.z - g.x) * (g.w - g.y);                            \
    nm_##r = ~(unsigned)m; }
    GTLOAD(0) GTLOAD(1) GTLOAD(2) GTLOAD(3)

    const int base = blockIdx.x * slice;
    const int rem  = N - base;
    const int nt   = ((rem < slice ? rem : slice) + 255) >> 8;

    for (int tile = 0; tile < nt; ++tile) {
        const int tb = base + (tile << 8);
        // ---- stage 256 anchors into LDS (coalesced) ---------------------
        {
            int gi = tb + tid;
            float4 ab = (gi < N) ? anchor[gi]
                                 : make_float4(0.f, 0.f, 0.f, 0.f);
            __syncthreads();           // previous tile's readers done
            s_abox[tid]  = ab;
            s_aarea[tid] = (ab.z - ab.x) * (ab.w - ab.y);
            __syncthreads();
        }

        const int jbase = tb + (w << 6);   // this wave's 64 anchors
        int myassign = -2;

        for (int jj = 0; jj < 64; ++jj) {
            const int j = (w << 6) + jj;
            float4 a     = s_abox[j];      // broadcast LDS read
            float area_a = s_aarea[j];
            unsigned nai = ~(unsigned)(jbase + jj);
            unsigned long long pa = 0;

#define PAIR(r) {                                                  \
            float ltx = fmaxf(a.x, gx1_##r);                       \
            float lty = fmaxf(a.y, gy1_##r);                       \
            float rbx = fminf(a.z, gx2_##r);                       \
            float rby = fminf(a.w, gy2_##r);                       \
            float ww  = fmaxf(rbx - ltx, 0.0f);                    \
            float hh  = fmaxf(rby - lty, 0.0f);                    \
            float inter = ww * hh;                                 \
            float iou = 0.0f;                                      \
            if (inter > 0.0f)                                      \
                iou = inter / ((area_a + ga_##r) - inter);         \
            unsigned ib = __float_as_uint(iou);                    \
            unsigned long long kt =                                \
                ((unsigned long long)ib << 32) | nai;              \
            INS3(t0_##r, t1_##r, t2_##r, kt);                      \
            unsigned long long kp =                                \
                ((unsigned long long)ib << 32) | nm_##r;           \
            pa = (kp > pa) ? kp : pa; }
            PAIR(0) PAIR(1) PAIR(2) PAIR(3)

            // wave-wide max of (iou, ~m): argmax with first-max tie-break
            for (int off = 1; off < 64; off <<= 1) {
                unsigned long long o = __shfl_xor(pa, off, 64);
                pa = (o > pa) ? o : pa;
            }
            // lane jj keeps the verdict for anchor jbase+jj
            float fiou = __uint_as_float((unsigned)(pa >> 32));
            int   mm   = (int)(~(unsigned)pa);
            int v = -2;
            if (fiou < NEG_THRESH) v = -1;
            if (fiou > POS_THRESH) v = mm;
            if (jj == lane) myassign = v;
        }

        int gout = jbase + lane;
        if (gout < N) out[gout] = myassign;
    }

    // ---- merge 4 waves' per-GT top-3 within the block -------------------
#define STORE_M(r) {                                               \
    s_merge[w][lane][r][0] = t0_##r;                               \
    s_merge[w][lane][r][1] = t1_##r;                               \
    s_merge[w][lane][r][2] = t2_##r; }
    __syncthreads();
    STORE_M(0) STORE_M(1) STORE_M(2) STORE_M(3)
    __syncthreads();

    if (tid < M) {
        const int l = tid & 63, rr = tid >> 6;
        unsigned long long r0 = 0, r1 = 0, r2 = 0;
        for (int wv = 0; wv < 4; ++wv) {
            INS3(r0, r1, r2, s_merge[wv][l][rr][0]);
            INS3(r0, r1, r2, s_merge[wv][l][rr][1]);
            INS3(r0, r1, r2, s_merge[wv][l][rr][2]);
        }
        // finalize-coalesced layout: [(blk*3 + k) * MPAD + m]
        const int blk = blockIdx.x;
        partial[((size_t)blk * 3 + 0) * MPAD + tid] = r0;
        partial[((size_t)blk * 3 + 1) * MPAD + tid] = r1;
        partial[((size_t)blk * 3 + 2) * MPAD + tid] = r2;
    }
}

// ---------------------------------------------------------------------------
// Finalize: merge per-block partials -> global top-3 per GT; apply claims.
// Single block, 1024 threads: 4 groups of 256 split the chunk range.
// ---------------------------------------------------------------------------
__global__ void __launch_bounds__(1024) k_finalize(
    const unsigned long long* __restrict__ partial, int* __restrict__ out,
    int M, int nblk)
{
    __shared__ unsigned long long sm[4][MPAD][3];   // 24 KB
    __shared__ int s_a[3 * MPAD];
    __shared__ int s_cv[3 * MPAD];

    const int tid = threadIdx.x;
    const int m   = tid & 255;
    const int g   = tid >> 8;

    const int tot = nblk * 3;
    const int per = (tot + 3) >> 2;
    const int c0  = g * per;
    const int c1  = (c0 + per < tot) ? c0 + per : tot;

    unsigned long long r0 = 0, r1 = 0, r2 = 0;
    if (m < M) {
        for (int c = c0; c < c1; ++c)
            INS3(r0, r1, r2, partial[(size_t)c * MPAD + m]);   // coalesced
    }
    sm[g][m][0] = r0; sm[g][m][1] = r1; sm[g][m][2] = r2;
    __syncthreads();

    if (tid < M) {
        unsigned long long q0 = 0, q1 = 0, q2 = 0;
        for (int g2 = 0; g2 < 4; ++g2) {
            INS3(q0, q1, q2, sm[g2][tid][0]);
            INS3(q0, q1, q2, sm[g2][tid][1]);
            INS3(q0, q1, q2, sm[g2][tid][2]);
        }
        float v0 = __uint_as_float((unsigned)(q0 >> 32));
        float v1 = __uint_as_float((unsigned)(q1 >> 32));
        float v2 = __uint_as_float((unsigned)(q2 >> 32));
        int a0 = (int)(~(unsigned)q0);
        int a1 = (int)(~(unsigned)q1);
        int a2 = (int)(~(unsigned)q2);

        int npos = (v0 > POS_THRESH) + (v1 > POS_THRESH) + (v2 > POS_THRESH);
        bool low = npos < 3;

        s_a[tid * 3 + 0] = a0;
        s_a[tid * 3 + 1] = a1;
        s_a[tid * 3 + 2] = a2;
        s_cv[tid * 3 + 0] = tid;                                   // k==0 forced
        s_cv[tid * 3 + 1] = (low && v1 > CLAIM_THRESH) ? tid : -1;
        s_cv[tid * 3 + 2] = (low && v2 > CLAIM_THRESH) ? tid : -1;
    }
    __syncthreads();

    // scatter-max: contested anchor -> highest claiming gt index wins
    const int tote = 3 * M;
    for (int e = tid; e < tote; e += 1024) {
        int cv = s_cv[e];
        if (cv < 0) continue;
        int a = s_a[e];
        bool win = true;
        for (int f = 0; f < tote; ++f) {
            if (s_cv[f] > cv && s_a[f] == a) { win = false; break; }
        }
        if (win) out[a] = cv;
    }
}

// ---------------------------------------------------------------------------
extern "C" void kernel_launch(void* const* d_in, const int* in_sizes, int n_in,
                              void* d_out, int out_size, void* d_ws, size_t ws_size,
                              hipStream_t stream) {
    const float4* anchor = (const float4*)d_in[0];
    const float4* gt     = (const float4*)d_in[1];
    int N = in_sizes[0] / 4;
    int M = in_sizes[1] / 4;
    int* out = (int*)d_out;
    unsigned long long* partial = (unsigned long long*)d_ws;

    // slice = anchors per block (multiple of 256); shrink block count until
    // the partial buffer fits in d_ws.
    int slice = 512;
    int nblk  = (N + slice - 1) / slice;
    while ((size_t)nblk * 3 * MPAD * sizeof(unsigned long long) > ws_size &&
           slice < (1 << 24)) {
        slice <<= 1;
        nblk = (N + slice - 1) / slice;
    }

    k_fused<<<nblk, 256, 0, stream>>>(anchor, gt, out, partial, N, M, slice);
    k_finalize<<<1, 1024, 0, stream>>>(partial, out, M, nblk);
}

// Round 4
// 327.003 us; speedup vs baseline: 3.1020x; 1.5395x over previous
//
#include <hip/hip_runtime.h>
#include <stdint.h>

// S3FD anchor assignment — fused single-pass + two-stage reduction.
// d_in[0]: anchor [N,4] f32, d_in[1]: gt [M,4] f32. d_out: assign [N] int32.
//
// Round 3 post-mortem: fused kernel is fine (~160 us); the single-block
// finalize was 330+ us at 0.17% occupancy (750k latency-bound INS3 merges on
// one CU). Fix: k_mid tree stage (128 blocks) + bigger slice (fewer partials)
// + 2-anchor-interleaved argmax butterfly in the fused kernel for shuffle ILP.
//
// Key encodings (exact jax semantics):
//   per-GT top-3:  key = (iou_bits << 32) | ~anchor_idx   (stable top_k)
//   per-anchor:    key = (iou_bits << 32) | ~gt_idx       (argmax first-max)

#define POS_THRESH 0.5f
#define NEG_THRESH 0.3f
#define CLAIM_THRESH 0.1f

constexpr int MPAD = 256;    // padded GT count (M = 200)

#define INS3(t0, t1, t2, k) do {                                  \
    if ((k) > (t2)) {                                             \
        if ((k) > (t0))      { t2 = t1; t1 = t0; t0 = (k); }      \
        else if ((k) > (t1)) { t2 = t1; t1 = (k); }               \
        else                 { t2 = (k); }                        \
    } } while (0)

// ---------------------------------------------------------------------------
// Fused kernel: base assignment + per-(block,GT) top-3 partials.
// grid = ceil(N/slice) blocks x 256 threads; slice is a multiple of 256.
// Lane l owns GTs {l, l+64, l+128, l+192} entirely in named-scalar registers.
// ---------------------------------------------------------------------------
__global__ void __launch_bounds__(256) k_fused(
    const float4* __restrict__ anchor, const float4* __restrict__ gt,
    int* __restrict__ out, unsigned long long* __restrict__ partial,
    int N, int M, int slice)
{
    __shared__ float4 s_abox[256];
    __shared__ float  s_aarea[256];
    __shared__ unsigned long long s_merge[4][64][4][3];   // 24 KB

    const int tid  = threadIdx.x;
    const int lane = tid & 63;
    const int w    = tid >> 6;

#define GTDECL(r)                                                  \
    float gx1_##r, gy1_##r, gx2_##r, gy2_##r, ga_##r;             \
    unsigned nm_##r;                                               \
    unsigned long long t0_##r = 0, t1_##r = 0, t2_##r = 0;
    GTDECL(0) GTDECL(1) GTDECL(2) GTDECL(3)

#define GTLOAD(r) {                                                \
    int m = lane + (r) * 64;                                       \
    float4 g = (m < M) ? gt[m] : make_float4(0.f, 0.f, 0.f, 0.f);  \
    gx1_##r = g.x; gy1_##r = g.y; gx2_##r = g.z; gy2_##r = g.w;    \
    ga_##r = (g.z - g.x) * (g.w - g.y);                            \
    nm_##r = ~(unsigned)m; }
    GTLOAD(0) GTLOAD(1) GTLOAD(2) GTLOAD(3)

    const int base = blockIdx.x * slice;
    const int rem  = N - base;
    const int nt   = ((rem < slice ? rem : slice) + 255) >> 8;

    for (int tile = 0; tile < nt; ++tile) {
        const int tb = base + (tile << 8);
        {
            int gi = tb + tid;
            float4 ab = (gi < N) ? anchor[gi]
                                 : make_float4(0.f, 0.f, 0.f, 0.f);
            __syncthreads();           // previous tile's readers done
            s_abox[tid]  = ab;
            s_aarea[tid] = (ab.z - ab.x) * (ab.w - ab.y);
            __syncthreads();
        }

        const int jbase = tb + (w << 6);   // this wave's 64 anchors
        int myassign = -2;

        // two anchors per iteration: independent argmax butterflies -> ILP
        for (int jj = 0; jj < 64; jj += 2) {
            const int j = (w << 6) + jj;
            float4 aA     = s_abox[j];
            float4 aB     = s_abox[j + 1];
            float  areaA  = s_aarea[j];
            float  areaB  = s_aarea[j + 1];
            unsigned naiA = ~(unsigned)(jbase + jj);
            unsigned naiB = ~(unsigned)(jbase + jj + 1);
            unsigned long long paA = 0, paB = 0;

#define PAIR2(r) {                                                 \
            float ltxA = fmaxf(aA.x, gx1_##r);                     \
            float ltyA = fmaxf(aA.y, gy1_##r);                     \
            float rbxA = fminf(aA.z, gx2_##r);                     \
            float rbyA = fminf(aA.w, gy2_##r);                     \
            float wA   = fmaxf(rbxA - ltxA, 0.0f);                 \
            float hA   = fmaxf(rbyA - ltyA, 0.0f);                 \
            float interA = wA * hA;                                \
            float iouA = 0.0f;                                     \
            if (interA > 0.0f)                                     \
                iouA = interA / ((areaA + ga_##r) - interA);       \
            unsigned ibA = __float_as_uint(iouA);                  \
            unsigned long long ktA =                               \
                ((unsigned long long)ibA << 32) | naiA;            \
            INS3(t0_##r, t1_##r, t2_##r, ktA);                     \
            unsigned long long kpA =                               \
                ((unsigned long long)ibA << 32) | nm_##r;          \
            paA = (kpA > paA) ? kpA : paA;                         \
            float ltxB = fmaxf(aB.x, gx1_##r);                     \
            float ltyB = fmaxf(aB.y, gy1_##r);                     \
            float rbxB = fminf(aB.z, gx2_##r);                     \
            float rbyB = fminf(aB.w, gy2_##r);                     \
            float wB   = fmaxf(rbxB - ltxB, 0.0f);                 \
            float hB   = fmaxf(rbyB - ltyB, 0.0f);                 \
            float interB = wB * hB;                                \
            float iouB = 0.0f;                                     \
            if (interB > 0.0f)                                     \
                iouB = interB / ((areaB + ga_##r) - interB);       \
            unsigned ibB = __float_as_uint(iouB);                  \
            unsigned long long ktB =                               \
                ((unsigned long long)ibB << 32) | naiB;            \
            INS3(t0_##r, t1_##r, t2_##r, ktB);                     \
            unsigned long long kpB =                               \
                ((unsigned long long)ibB << 32) | nm_##r;          \
            paB = (kpB > paB) ? kpB : paB; }
            PAIR2(0) PAIR2(1) PAIR2(2) PAIR2(3)

            // interleaved wave-wide max of (iou, ~m) for both anchors
            for (int off = 1; off < 64; off <<= 1) {
                unsigned long long oA = __shfl_xor(paA, off, 64);
                unsigned long long oB = __shfl_xor(paB, off, 64);
                paA = (oA > paA) ? oA : paA;
                paB = (oB > paB) ? oB : paB;
            }
            float fA = __uint_as_float((unsigned)(paA >> 32));
            int   mA = (int)(~(unsigned)paA);
            int vA = -2;
            if (fA < NEG_THRESH) vA = -1;
            if (fA > POS_THRESH) vA = mA;
            float fB = __uint_as_float((unsigned)(paB >> 32));
            int   mB = (int)(~(unsigned)paB);
            int vB = -2;
            if (fB < NEG_THRESH) vB = -1;
            if (fB > POS_THRESH) vB = mB;
            if (jj == lane)     myassign = vA;
            if (jj + 1 == lane) myassign = vB;
        }

        int gout = jbase + lane;
        if (gout < N) out[gout] = myassign;
    }

    // ---- merge 4 waves' per-GT top-3 within the block -------------------
#define STORE_M(r) {                                               \
    s_merge[w][lane][r][0] = t0_##r;                               \
    s_merge[w][lane][r][1] = t1_##r;                               \
    s_merge[w][lane][r][2] = t2_##r; }
    __syncthreads();
    STORE_M(0) STORE_M(1) STORE_M(2) STORE_M(3)
    __syncthreads();

    if (tid < M) {
        const int l = tid & 63, rr = tid >> 6;
        unsigned long long r0 = 0, r1 = 0, r2 = 0;
        for (int wv = 0; wv < 4; ++wv) {
            INS3(r0, r1, r2, s_merge[wv][l][rr][0]);
            INS3(r0, r1, r2, s_merge[wv][l][rr][1]);
            INS3(r0, r1, r2, s_merge[wv][l][rr][2]);
        }
        const int blk = blockIdx.x;
        partial[((size_t)blk * 3 + 0) * MPAD + tid] = r0;
        partial[((size_t)blk * 3 + 1) * MPAD + tid] = r1;
        partial[((size_t)blk * 3 + 2) * MPAD + tid] = r2;
    }
}

// ---------------------------------------------------------------------------
// Mid-stage reduce: G2 blocks x 256 threads; thread m merges its chunk range.
// ---------------------------------------------------------------------------
__global__ void __launch_bounds__(256) k_mid(
    const unsigned long long* __restrict__ partial,
    unsigned long long* __restrict__ mid, int M, int nblk, int G2)
{
    const int m = threadIdx.x;
    const int b = blockIdx.x;
    const int per = (nblk + G2 - 1) / G2;
    const int c0 = b * per;
    const int c1 = (c0 + per < nblk) ? c0 + per : nblk;

    unsigned long long r0 = 0, r1 = 0, r2 = 0;
    if (m < M) {
        for (int c = c0; c < c1; ++c) {
            const unsigned long long* p = partial + (size_t)c * 3 * MPAD + m;
            INS3(r0, r1, r2, p[0 * MPAD]);
            INS3(r0, r1, r2, p[1 * MPAD]);
            INS3(r0, r1, r2, p[2 * MPAD]);
        }
    }
    mid[((size_t)b * 3 + 0) * MPAD + m] = r0;
    mid[((size_t)b * 3 + 1) * MPAD + m] = r1;
    mid[((size_t)b * 3 + 2) * MPAD + m] = r2;
}

// ---------------------------------------------------------------------------
// Finalize: merge mid partials -> global top-3 per GT; apply forced claims.
// Single block, 1024 threads: 4 groups of 256 split the chunk range.
// ---------------------------------------------------------------------------
__global__ void __launch_bounds__(1024) k_finalize(
    const unsigned long long* __restrict__ mid, int* __restrict__ out,
    int M, int nmid)
{
    __shared__ unsigned long long sm[4][MPAD][3];   // 24 KB
    __shared__ int s_a[3 * MPAD];
    __shared__ int s_cv[3 * MPAD];

    const int tid = threadIdx.x;
    const int m   = tid & 255;
    const int g   = tid >> 8;

    const int tot = nmid * 3;
    const int per = (tot + 3) >> 2;
    const int c0  = g * per;
    const int c1  = (c0 + per < tot) ? c0 + per : tot;

    unsigned long long r0 = 0, r1 = 0, r2 = 0;
    if (m < M) {
        for (int c = c0; c < c1; ++c)
            INS3(r0, r1, r2, mid[(size_t)c * MPAD + m]);   // coalesced
    }
    sm[g][m][0] = r0; sm[g][m][1] = r1; sm[g][m][2] = r2;
    __syncthreads();

    if (tid < M) {
        unsigned long long q0 = 0, q1 = 0, q2 = 0;
        for (int g2 = 0; g2 < 4; ++g2) {
            INS3(q0, q1, q2, sm[g2][tid][0]);
            INS3(q0, q1, q2, sm[g2][tid][1]);
            INS3(q0, q1, q2, sm[g2][tid][2]);
        }
        float v0 = __uint_as_float((unsigned)(q0 >> 32));
        float v1 = __uint_as_float((unsigned)(q1 >> 32));
        float v2 = __uint_as_float((unsigned)(q2 >> 32));
        int a0 = (int)(~(unsigned)q0);
        int a1 = (int)(~(unsigned)q1);
        int a2 = (int)(~(unsigned)q2);

        int npos = (v0 > POS_THRESH) + (v1 > POS_THRESH) + (v2 > POS_THRESH);
        bool low = npos < 3;

        s_a[tid * 3 + 0] = a0;
        s_a[tid * 3 + 1] = a1;
        s_a[tid * 3 + 2] = a2;
        s_cv[tid * 3 + 0] = tid;                                   // k==0 forced
        s_cv[tid * 3 + 1] = (low && v1 > CLAIM_THRESH) ? tid : -1;
        s_cv[tid * 3 + 2] = (low && v2 > CLAIM_THRESH) ? tid : -1;
    }
    __syncthreads();

    // scatter-max: contested anchor -> highest claiming gt index wins
    const int tote = 3 * M;
    for (int e = tid; e < tote; e += 1024) {
        int cv = s_cv[e];
        if (cv < 0) continue;
        int a = s_a[e];
        bool win = true;
        for (int f = 0; f < tote; ++f) {
            if (s_cv[f] > cv && s_a[f] == a) { win = false; break; }
        }
        if (win) out[a] = cv;
    }
}

// ---------------------------------------------------------------------------
extern "C" void kernel_launch(void* const* d_in, const int* in_sizes, int n_in,
                              void* d_out, int out_size, void* d_ws, size_t ws_size,
                              hipStream_t stream) {
    const float4* anchor = (const float4*)d_in[0];
    const float4* gt     = (const float4*)d_in[1];
    int N = in_sizes[0] / 4;
    int M = in_sizes[1] / 4;
    int* out = (int*)d_out;

    // slice = anchors per block (multiple of 256)
    int slice = 1024;
    int nblk  = (N + slice - 1) / slice;
    int G2    = (nblk < 128) ? nblk : 128;
    while ((size_t)(nblk + G2) * 3 * MPAD * sizeof(unsigned long long) > ws_size &&
           slice < (1 << 24)) {
        slice <<= 1;
        nblk = (N + slice - 1) / slice;
        G2   = (nblk < 128) ? nblk : 128;
    }

    unsigned long long* partial = (unsigned long long*)d_ws;
    unsigned long long* mid     = partial + (size_t)nblk * 3 * MPAD;

    k_fused<<<nblk, 256, 0, stream>>>(anchor, gt, out, partial, N, M, slice);
    k_mid<<<G2, 256, 0, stream>>>(partial, mid, M, nblk, G2);
    k_finalize<<<1, 1024, 0, stream>>>(mid, out, M, G2);
}

// Round 5
// 267.418 us; speedup vs baseline: 3.7932x; 1.2228x over previous
//
#include <hip/hip_runtime.h>
#include <stdint.h>

// S3FD anchor assignment — fused single-pass + two-stage reduction.
// d_in[0]: anchor [N,4] f32, d_in[1]: gt [M,4] f32. d_out: assign [N] int32.
//
// Round 4 post-mortem: k_fused 218 us @ VALUBusy 65%, Occupancy 20% —
// grid-limited (489 blocks / 256 CUs). This round: slice 512 (977 blocks,
// ~4/CU) and a cheaper per-anchor argmax: u32 iou-bits butterfly + ballot/ctz
// index resolution (tie-break m = lane + 64r: smallest r then smallest lane
// == smallest m == jax argmax first-max). Partial stride = M (not 256) to
// keep the workspace within the proven-good budget.
//
// Key encoding (exact jax semantics), per-GT top-3:
//   key = (iou_bits << 32) | ~anchor_idx    (stable top_k: higher iou, then
//                                            lower anchor index wins)

#define POS_THRESH 0.5f
#define NEG_THRESH 0.3f
#define CLAIM_THRESH 0.1f

constexpr int MPAD = 256;    // LDS-side padded GT count (M = 200)

#define INS3(t0, t1, t2, k) do {                                  \
    if ((k) > (t2)) {                                             \
        if ((k) > (t0))      { t2 = t1; t1 = t0; t0 = (k); }      \
        else if ((k) > (t1)) { t2 = t1; t1 = (k); }               \
        else                 { t2 = (k); }                        \
    } } while (0)

// ---------------------------------------------------------------------------
// Fused kernel: base assignment + per-(block,GT) top-3 partials.
// grid = ceil(N/slice) blocks x 256 threads; slice is a multiple of 256.
// Lane l owns GTs {l, l+64, l+128, l+192} entirely in named-scalar registers.
// ---------------------------------------------------------------------------
__global__ void __launch_bounds__(256) k_fused(
    const float4* __restrict__ anchor, const float4* __restrict__ gt,
    int* __restrict__ out, unsigned long long* __restrict__ partial,
    int N, int M, int slice)
{
    __shared__ float4 s_abox[256];
    __shared__ float  s_aarea[256];
    __shared__ unsigned long long s_merge[4][64][4][3];   // 24 KB

    const int tid  = threadIdx.x;
    const int lane = tid & 63;
    const int w    = tid >> 6;

#define GTDECL(r)                                                  \
    float gx1_##r, gy1_##r, gx2_##r, gy2_##r, ga_##r;             \
    unsigned long long t0_##r = 0, t1_##r = 0, t2_##r = 0;
    GTDECL(0) GTDECL(1) GTDECL(2) GTDECL(3)

#define GTLOAD(r) {                                                \
    int m = lane + (r) * 64;                                       \
    float4 g = (m < M) ? gt[m] : make_float4(0.f, 0.f, 0.f, 0.f);  \
    gx1_##r = g.x; gy1_##r = g.y; gx2_##r = g.z; gy2_##r = g.w;    \
    ga_##r = (g.z - g.x) * (g.w - g.y); }
    GTLOAD(0) GTLOAD(1) GTLOAD(2) GTLOAD(3)

    const int base = blockIdx.x * slice;
    const int rem  = N - base;
    const int nt   = ((rem < slice ? rem : slice) + 255) >> 8;

    for (int tile = 0; tile < nt; ++tile) {
        const int tb = base + (tile << 8);
        {
            int gi = tb + tid;
            float4 ab = (gi < N) ? anchor[gi]
                                 : make_float4(0.f, 0.f, 0.f, 0.f);
            __syncthreads();           // previous tile's readers done
            s_abox[tid]  = ab;
            s_aarea[tid] = (ab.z - ab.x) * (ab.w - ab.y);
            __syncthreads();
        }

        const int jbase = tb + (w << 6);   // this wave's 64 anchors
        int myassign = -2;

        // two anchors per iteration: independent reductions -> ILP
        for (int jj = 0; jj < 64; jj += 2) {
            const int j = (w << 6) + jj;
            float4 aA     = s_abox[j];
            float4 aB     = s_abox[j + 1];
            float  areaA  = s_aarea[j];
            float  areaB  = s_aarea[j + 1];
            unsigned naiA = ~(unsigned)(jbase + jj);
            unsigned naiB = ~(unsigned)(jbase + jj + 1);
            unsigned ibA_0, ibA_1, ibA_2, ibA_3;
            unsigned ibB_0, ibB_1, ibB_2, ibB_3;

#define PAIR2(r) {                                                 \
            float ltxA = fmaxf(aA.x, gx1_##r);                     \
            float ltyA = fmaxf(aA.y, gy1_##r);                     \
            float rbxA = fminf(aA.z, gx2_##r);                     \
            float rbyA = fminf(aA.w, gy2_##r);                     \
            float wA   = fmaxf(rbxA - ltxA, 0.0f);                 \
            float hA   = fmaxf(rbyA - ltyA, 0.0f);                 \
            float interA = wA * hA;                                \
            float iouA = 0.0f;                                     \
            if (interA > 0.0f)                                     \
                iouA = interA / ((areaA + ga_##r) - interA);       \
            ibA_##r = __float_as_uint(iouA);                       \
            unsigned long long ktA =                               \
                ((unsigned long long)ibA_##r << 32) | naiA;        \
            INS3(t0_##r, t1_##r, t2_##r, ktA);                     \
            float ltxB = fmaxf(aB.x, gx1_##r);                     \
            float ltyB = fmaxf(aB.y, gy1_##r);                     \
            float rbxB = fminf(aB.z, gx2_##r);                     \
            float rbyB = fminf(aB.w, gy2_##r);                     \
            float wB   = fmaxf(rbxB - ltxB, 0.0f);                 \
            float hB   = fmaxf(rbyB - ltyB, 0.0f);                 \
            float interB = wB * hB;                                \
            float iouB = 0.0f;                                     \
            if (interB > 0.0f)                                     \
                iouB = interB / ((areaB + ga_##r) - interB);       \
            ibB_##r = __float_as_uint(iouB);                       \
            unsigned long long ktB =                               \
                ((unsigned long long)ibB_##r << 32) | naiB;        \
            INS3(t0_##r, t1_##r, t2_##r, ktB); }
            PAIR2(0) PAIR2(1) PAIR2(2) PAIR2(3)

            // per-lane max iou bits over 4 slots, then u32 wave butterfly
            unsigned mxA = max(max(ibA_0, ibA_1), max(ibA_2, ibA_3));
            unsigned mxB = max(max(ibB_0, ibB_1), max(ibB_2, ibB_3));
            for (int off = 1; off < 64; off <<= 1) {
                unsigned oA = __shfl_xor(mxA, off, 64);
                unsigned oB = __shfl_xor(mxB, off, 64);
                mxA = (oA > mxA) ? oA : mxA;
                mxB = (oB > mxB) ? oB : mxB;
            }

            // argmax index: smallest m = smallest slot r, then smallest lane
            unsigned long long bA0 = __ballot(ibA_0 == mxA);
            unsigned long long bA1 = __ballot(ibA_1 == mxA);
            unsigned long long bA2 = __ballot(ibA_2 == mxA);
            unsigned long long bA3 = __ballot(ibA_3 == mxA);
            int mA;
            if      (bA0) mA =       __builtin_ctzll(bA0);
            else if (bA1) mA =  64 + __builtin_ctzll(bA1);
            else if (bA2) mA = 128 + __builtin_ctzll(bA2);
            else          mA = 192 + __builtin_ctzll(bA3);

            unsigned long long bB0 = __ballot(ibB_0 == mxB);
            unsigned long long bB1 = __ballot(ibB_1 == mxB);
            unsigned long long bB2 = __ballot(ibB_2 == mxB);
            unsigned long long bB3 = __ballot(ibB_3 == mxB);
            int mB;
            if      (bB0) mB =       __builtin_ctzll(bB0);
            else if (bB1) mB =  64 + __builtin_ctzll(bB1);
            else if (bB2) mB = 128 + __builtin_ctzll(bB2);
            else          mB = 192 + __builtin_ctzll(bB3);

            // thresholds as unsigned bit-compares (iou >= 0 -> monotone)
            int vA = -2;
            if (mxA < __float_as_uint(NEG_THRESH)) vA = -1;
            if (mxA > __float_as_uint(POS_THRESH)) vA = mA;
            int vB = -2;
            if (mxB < __float_as_uint(NEG_THRESH)) vB = -1;
            if (mxB > __float_as_uint(POS_THRESH)) vB = mB;
            if (jj == lane)     myassign = vA;
            if (jj + 1 == lane) myassign = vB;
        }

        int gout = jbase + lane;
        if (gout < N) out[gout] = myassign;
    }

    // ---- merge 4 waves' per-GT top-3 within the block -------------------
#define STORE_M(r) {                                               \
    s_merge[w][lane][r][0] = t0_##r;                               \
    s_merge[w][lane][r][1] = t1_##r;                               \
    s_merge[w][lane][r][2] = t2_##r; }
    __syncthreads();
    STORE_M(0) STORE_M(1) STORE_M(2) STORE_M(3)
    __syncthreads();

    if (tid < M) {
        const int l = tid & 63, rr = tid >> 6;
        unsigned long long r0 = 0, r1 = 0, r2 = 0;
        for (int wv = 0; wv < 4; ++wv) {
            INS3(r0, r1, r2, s_merge[wv][l][rr][0]);
            INS3(r0, r1, r2, s_merge[wv][l][rr][1]);
            INS3(r0, r1, r2, s_merge[wv][l][rr][2]);
        }
        const int blk = blockIdx.x;
        partial[((size_t)blk * 3 + 0) * M + tid] = r0;
        partial[((size_t)blk * 3 + 1) * M + tid] = r1;
        partial[((size_t)blk * 3 + 2) * M + tid] = r2;
    }
}

// ---------------------------------------------------------------------------
// Mid-stage reduce: G2 blocks x 256 threads; thread m merges its chunk range.
// ---------------------------------------------------------------------------
__global__ void __launch_bounds__(256) k_mid(
    const unsigned long long* __restrict__ partial,
    unsigned long long* __restrict__ mid, int M, int nblk, int G2)
{
    const int m = threadIdx.x;
    const int b = blockIdx.x;
    const int per = (nblk + G2 - 1) / G2;
    const int c0 = b * per;
    const int c1 = (c0 + per < nblk) ? c0 + per : nblk;

    if (m < M) {
        unsigned long long r0 = 0, r1 = 0, r2 = 0;
        for (int c = c0; c < c1; ++c) {
            const unsigned long long* p = partial + (size_t)c * 3 * M + m;
            INS3(r0, r1, r2, p[0 * M]);
            INS3(r0, r1, r2, p[1 * M]);
            INS3(r0, r1, r2, p[2 * M]);
        }
        mid[((size_t)b * 3 + 0) * M + m] = r0;
        mid[((size_t)b * 3 + 1) * M + m] = r1;
        mid[((size_t)b * 3 + 2) * M + m] = r2;
    }
}

// ---------------------------------------------------------------------------
// Finalize: merge mid partials -> global top-3 per GT; apply forced claims.
// Single block, 1024 threads: 4 groups of 256 split the chunk range.
// ---------------------------------------------------------------------------
__global__ void __launch_bounds__(1024) k_finalize(
    const unsigned long long* __restrict__ mid, int* __restrict__ out,
    int M, int nmid)
{
    __shared__ unsigned long long sm[4][MPAD][3];   // 24 KB
    __shared__ int s_a[3 * MPAD];
    __shared__ int s_cv[3 * MPAD];

    const int tid = threadIdx.x;
    const int m   = tid & 255;
    const int g   = tid >> 8;

    const int tot = nmid * 3;
    const int per = (tot + 3) >> 2;
    const int c0  = g * per;
    const int c1  = (c0 + per < tot) ? c0 + per : tot;

    unsigned long long r0 = 0, r1 = 0, r2 = 0;
    if (m < M) {
        for (int c = c0; c < c1; ++c)
            INS3(r0, r1, r2, mid[(size_t)c * M + m]);   // coalesced
    }
    sm[g][m][0] = r0; sm[g][m][1] = r1; sm[g][m][2] = r2;
    __syncthreads();

    if (tid < M) {
        unsigned long long q0 = 0, q1 = 0, q2 = 0;
        for (int g2 = 0; g2 < 4; ++g2) {
            INS3(q0, q1, q2, sm[g2][tid][0]);
            INS3(q0, q1, q2, sm[g2][tid][1]);
            INS3(q0, q1, q2, sm[g2][tid][2]);
        }
        float v0 = __uint_as_float((unsigned)(q0 >> 32));
        float v1 = __uint_as_float((unsigned)(q1 >> 32));
        float v2 = __uint_as_float((unsigned)(q2 >> 32));
        int a0 = (int)(~(unsigned)q0);
        int a1 = (int)(~(unsigned)q1);
        int a2 = (int)(~(unsigned)q2);

        int npos = (v0 > POS_THRESH) + (v1 > POS_THRESH) + (v2 > POS_THRESH);
        bool low = npos < 3;

        s_a[tid * 3 + 0] = a0;
        s_a[tid * 3 + 1] = a1;
        s_a[tid * 3 + 2] = a2;
        s_cv[tid * 3 + 0] = tid;                                   // k==0 forced
        s_cv[tid * 3 + 1] = (low && v1 > CLAIM_THRESH) ? tid : -1;
        s_cv[tid * 3 + 2] = (low && v2 > CLAIM_THRESH) ? tid : -1;
    }
    __syncthreads();

    // scatter-max: contested anchor -> highest claiming gt index wins
    const int tote = 3 * M;
    for (int e = tid; e < tote; e += 1024) {
        int cv = s_cv[e];
        if (cv < 0) continue;
        int a = s_a[e];
        bool win = true;
        for (int f = 0; f < tote; ++f) {
            if (s_cv[f] > cv && s_a[f] == a) { win = false; break; }
        }
        if (win) out[a] = cv;
    }
}

// ---------------------------------------------------------------------------
extern "C" void kernel_launch(void* const* d_in, const int* in_sizes, int n_in,
                              void* d_out, int out_size, void* d_ws, size_t ws_size,
                              hipStream_t stream) {
    const float4* anchor = (const float4*)d_in[0];
    const float4* gt     = (const float4*)d_in[1];
    int N = in_sizes[0] / 4;
    int M = in_sizes[1] / 4;
    int* out = (int*)d_out;

    // slice = anchors per block (multiple of 256)
    int slice = 512;
    int nblk  = (N + slice - 1) / slice;
    int G2    = (nblk < 128) ? nblk : 128;
    while ((size_t)(nblk + G2) * 3 * M * sizeof(unsigned long long) > ws_size &&
           slice < (1 << 24)) {
        slice <<= 1;
        nblk = (N + slice - 1) / slice;
        G2   = (nblk < 128) ? nblk : 128;
    }

    unsigned long long* partial = (unsigned long long*)d_ws;
    unsigned long long* mid     = partial + (size_t)nblk * 3 * M;

    k_fused<<<nblk, 256, 0, stream>>>(anchor, gt, out, partial, N, M, slice);
    k_mid<<<G2, 256, 0, stream>>>(partial, mid, M, nblk, G2);
    k_finalize<<<1, 1024, 0, stream>>>(mid, out, M, G2);
}